// Round 12
// baseline (705.355 us; speedup 1.0000x reference)
//
#include <hip/hip_runtime.h>
#include <hip/hip_bf16.h>
#include <math.h>

typedef unsigned short ushort_t;
typedef short short8 __attribute__((ext_vector_type(8)));
typedef float f32x4 __attribute__((ext_vector_type(4)));

#define N_TOK 512
#define EMBED 1024
#define INTER 4096
#define NCAT  5120   /* INTER + EMBED */
#define MROWS 24576  /* 48 * 512 */

__device__ __forceinline__ ushort_t f2bf(float f) {
  union { float f; unsigned int u; } c; c.f = f;
  unsigned int u = c.u;
  unsigned int r = u + 0x7fffu + ((u >> 16) & 1u);
  return (ushort_t)(r >> 16);
}

__device__ __forceinline__ void gld_lds16(const void* g, void* l) {
  __builtin_amdgcn_global_load_lds(
      (const __attribute__((address_space(1))) void*)g,
      (__attribute__((address_space(3))) void*)l, 16, 0, 0);
}

// ---- merged prep kernels ------------------------------------------------
__global__ void prep_w(const float* __restrict__ Wl, const float* __restrict__ Wr,
                       const float* __restrict__ Wo,
                       const float* __restrict__ bl, const float* __restrict__ br,
                       ushort_t* __restrict__ wout,
                       ushort_t* __restrict__ w0, ushort_t* __restrict__ w1,
                       ushort_t* __restrict__ w2, float* __restrict__ bcat) {
  int i = blockIdx.x * 256 + threadIdx.x;
  if (i < NCAT) { bcat[i] = (i < INTER) ? bl[i] : br[i - INTER]; return; }
  i -= NCAT;
  if (i < EMBED * INTER) { wout[i] = f2bf(Wo[i]); return; }
  i -= EMBED * INTER;
  ushort_t* dst; int Kpad, P3;
  if (i < NCAT * 64)            { dst = w0; Kpad = 64;  P3 = 48; }
  else if (i < NCAT * 160)      { i -= NCAT * 64;  dst = w1; Kpad = 96;  P3 = 96; }
  else if (i < NCAT * 352)      { i -= NCAT * 160; dst = w2; Kpad = 192; P3 = 192; }
  else return;
  const int r = i / Kpad, j = i - r * Kpad;
  float v = 0.f;
  if (j < P3) {
    float scale = 96.0f / (float)P3;
    float src = (j + 0.5f) * scale - 0.5f;
    src = fminf(fmaxf(src, 0.0f), 95.0f);
    int i0 = (int)src;
    int i1 = min(i0 + 1, 95);
    float tt = src - (float)i0;
    const float* Wrow = (r < INTER) ? (Wl + (size_t)r * 96)
                                    : (Wr + (size_t)(r - INTER) * 96);
    v = Wrow[i0] * (1.f - tt) + Wrow[i1] * tt;
  }
  dst[i] = f2bf(v);
}

__global__ void prep_x(const float* __restrict__ x0, const float* __restrict__ m0,
                       const float* __restrict__ t0,
                       const float* __restrict__ x1, const float* __restrict__ m1,
                       const float* __restrict__ t1,
                       const float* __restrict__ x2, const float* __restrict__ m2,
                       const float* __restrict__ t2,
                       ushort_t* __restrict__ d0, ushort_t* __restrict__ d1,
                       ushort_t* __restrict__ d2) {
  int i = blockIdx.x * 256 + threadIdx.x;
  const float *x, *m, *t; ushort_t* dst; int p, Kpad;
  if (i < 8192 * 64)            { x = x0; m = m0; t = t0; dst = d0; p = 16; Kpad = 64; }
  else if (i < 8192 * 160)      { i -= 8192 * 64;  x = x1; m = m1; t = t1; dst = d1; p = 32; Kpad = 96; }
  else if (i < 8192 * 352)      { i -= 8192 * 160; x = x2; m = m2; t = t2; dst = d2; p = 64; Kpad = 192; }
  else return;
  const int r = i / Kpad, j = i - r * Kpad;
  float v = 0.f;
  const int p3 = 3 * p;
  if (j < p3) {
    size_t base = (size_t)r * p;
    if (j < p)           v = x[base + j];
    else if (j < 2 * p)  v = m[base + j - p];
    else                 v = t[base + j - 2 * p];
  }
  dst[i] = f2bf(v);
}

// ---- phase-1: merged 3-group 128x128 GEMM (R3/R7 interior, proven) ------
__global__ __launch_bounds__(256)
void gemm128p1g(const ushort_t* __restrict__ A0, const ushort_t* __restrict__ A1,
                const ushort_t* __restrict__ A2,
                const ushort_t* __restrict__ B0w, const ushort_t* __restrict__ B1w,
                const ushort_t* __restrict__ B2w,
                const float* __restrict__ bias,
                ushort_t* __restrict__ hidden, float* __restrict__ outp,
                const int* __restrict__ i0, const int* __restrict__ i1,
                const int* __restrict__ i2) {
  __shared__ __align__(16) ushort_t lA[2][128 * 32];
  __shared__ __align__(16) ushort_t lB[2][128 * 32];
  const int t = threadIdx.x;
  const int wave = t >> 6, lane = t & 63;
  const int gm = blockIdx.x >> 6;             // group 0/1/2
  const int tm = (blockIdx.x & 63) * 128;     // within-group row tile
  const int tn = blockIdx.y * 128;
  const ushort_t* A = (gm == 0) ? A0 : (gm == 1) ? A1 : A2;
  const ushort_t* B = (gm == 0) ? B0w : (gm == 1) ? B1w : B2w;
  const int* idxg   = (gm == 0) ? i0 : (gm == 1) ? i1 : i2;
  const int Kpad    = (gm == 0) ? 64 : (gm == 1) ? 96 : 192;

  const int chunk = wave * 2;
  const int srow = chunk * 16 + (lane >> 2);
  const int scol = (((lane & 3) ^ ((lane >> 3) & 3)) * 8);
  const ushort_t* gA0 = A + (size_t)(tm + srow) * Kpad + scol;
  const ushort_t* gA1 = gA0 + (size_t)16 * Kpad;
  const ushort_t* gB0 = B + (size_t)(tn + srow) * Kpad + scol;
  const ushort_t* gB1 = gB0 + (size_t)16 * Kpad;
  const int ldsOff0 = chunk * 512;
  const int ldsOff1 = ldsOff0 + 512;

  const int wr = wave >> 1, wc = wave & 1;
  const f32x4 zero = {0.f, 0.f, 0.f, 0.f};
  f32x4 acc[4][4];
#pragma unroll
  for (int m2 = 0; m2 < 4; ++m2)
#pragma unroll
    for (int n2 = 0; n2 < 4; ++n2) acc[m2][n2] = zero;

  const int xf = ((lane & 15) >> 1) & 3;
  const int fcol = (((lane >> 4) ^ xf)) * 8;
  const int aoff = (wr * 64 + (lane & 15)) * 32 + fcol;
  const int boff = (wc * 64 + (lane & 15)) * 32 + fcol;

  const int nk = Kpad >> 5;
  gld_lds16(gA0, &lA[0][ldsOff0]); gld_lds16(gA1, &lA[0][ldsOff1]);
  gld_lds16(gB0, &lB[0][ldsOff0]); gld_lds16(gB1, &lB[0][ldsOff1]);
  gA0 += 32; gA1 += 32; gB0 += 32; gB1 += 32;

  for (int kk = 0; kk < nk; ++kk) {
    const int cur = kk & 1;
    if (kk + 1 < nk) {
      const int nxt = cur ^ 1;
      gld_lds16(gA0, &lA[nxt][ldsOff0]); gld_lds16(gA1, &lA[nxt][ldsOff1]);
      gld_lds16(gB0, &lB[nxt][ldsOff0]); gld_lds16(gB1, &lB[nxt][ldsOff1]);
      gA0 += 32; gA1 += 32; gB0 += 32; gB1 += 32;
      asm volatile("s_waitcnt vmcnt(4)" ::: "memory");
    } else {
      asm volatile("s_waitcnt vmcnt(0)" ::: "memory");
    }
    __builtin_amdgcn_s_barrier();
    asm volatile("" ::: "memory");

    const ushort_t* pa = &lA[cur][0] + aoff;
    const ushort_t* pb = &lB[cur][0] + boff;
    short8 aF[4], bF[4];
#pragma unroll
    for (int m2 = 0; m2 < 4; ++m2) aF[m2] = *(const short8*)(pa + m2 * 16 * 32);
#pragma unroll
    for (int n2 = 0; n2 < 4; ++n2) bF[n2] = *(const short8*)(pb + n2 * 16 * 32);
#pragma unroll
    for (int m2 = 0; m2 < 4; ++m2)
#pragma unroll
      for (int n2 = 0; n2 < 4; ++n2)
        acc[m2][n2] = __builtin_amdgcn_mfma_f32_16x16x32_bf16(
            aF[m2], bF[n2], acc[m2][n2], 0, 0, 0);
    __builtin_amdgcn_s_barrier();
    asm volatile("" ::: "memory");
  }

  const int layer = idxg[tm >> 9];
  const int rowBase = layer * N_TOK + (tm & (N_TOK - 1));

#pragma unroll
  for (int m2 = 0; m2 < 4; ++m2) {
#pragma unroll
    for (int n2 = 0; n2 < 4; ++n2) {
      const int colg = tn + wc * 64 + n2 * 16 + (lane & 15);
      const float bv = bias[colg];
#pragma unroll
      for (int r = 0; r < 4; ++r) {
        const int rowl = wr * 64 + m2 * 16 + (lane >> 4) * 4 + r;
        const float v = acc[m2][n2][r];
        const int grow = rowBase + rowl;
        if (colg < INTER) {
          float h = v + bv;
          h = h / (1.f + expf(-h));
          hidden[(size_t)grow * INTER + colg] = f2bf(h);
        } else {
          outp[(size_t)grow * EMBED + (colg - INTER)] = v + bv;
        }
      }
    }
  }
}

// ---- phase-2: 192x128 full-K GEMM, B direct global->VGPR ---------------
// A = hidden [24576][4096] bf16 staged via global_load_lds (LDS A-only,
// 2 x 24 KB); B = wout [1024][4096] bf16 loaded straight into MFMA
// fragment registers from global (panel = 1 MB, L2-resident, reused by
// 16 blocks/XCD), double-buffered one KT ahead. Removes 48 KB/blk-KT of
// LDS traffic -> MFMA becomes the critical pipe.
// Ledger: 14 VMEM ops/KT (B 8 + A 6, any internal order); WAITV(14)
// before the trailing barrier drains exactly A(t+1)+B(t). Compiler
// inserts its own counted waits for B register operands.
// WAR: STGA6(buf) placed after the mid-KT barrier; all waves' aF reads
// of buf were consumed by the nh0 MFMA cluster before that barrier.
#define ABUF 24576

__global__ __launch_bounds__(256, 2)
void gemm192x128(const ushort_t* __restrict__ A, const ushort_t* __restrict__ Bw,
                 const float* __restrict__ bias, float* __restrict__ outp) {
  __shared__ __align__(16) char smem[2 * ABUF];
  const int tid = threadIdx.x;
  const int w = tid >> 6, l = tid & 63;

  const int L = blockIdx.x;
  const int xcd = L & 7, j = L >> 3;          // j in [0,128)
  const int nt = j & 7, mtl = j >> 3;         // nt fastest: A-slab reuse
  const int tm = (xcd * 16 + mtl) * 192, tn = nt * 128;

  // A staging source pointers (pre-swizzled global, linear LDS dest)
  const ushort_t* pA[6]; int dA[6];
#pragma unroll
  for (int jj = 0; jj < 6; ++jj) {
    const int q = w * 6 + jj;                 // 0..23
    const int ks = q / 12, rb = q % 12;
    const int row = rb * 16 + (l >> 2);
    const int c = (l & 3) ^ ((row >> 1) & 3);
    pA[jj] = A + (size_t)(tm + row) * 4096 + ks * 32 + c * 8;
    dA[jj] = ks * 12288 + rb * 1024;
  }

#define STGA6(BB) do { _Pragma("unroll") for (int jj = 0; jj < 6; ++jj) \
    gld_lds16(pA[jj], smem + (BB) + dA[jj]); \
    _Pragma("unroll") for (int jj = 0; jj < 6; ++jj) pA[jj] += 64; } while (0)

  // fragment read bases
  const int wr = w >> 1, wc = w & 1;          // 2M x 2N
  const int xl = ((l & 15) >> 1) & 3;
  const int cx = ((l >> 4) ^ xl) * 16;
  const int aBase = (wr * 96 + (l & 15)) * 64 + cx;
  // B fragment global base: lane l covers n = tn+wc*64+(l&15)(+nh*32+np*16),
  // k = koff + ks*32 + (l>>4)*8  (exact MFMA B layout)
  const ushort_t* bGlob = Bw + (size_t)(tn + wc * 64 + (l & 15)) * 4096 + ((l >> 4) * 8);

  f32x4 acc[6][4];
  const f32x4 zero = {0.f, 0.f, 0.f, 0.f};
#pragma unroll
  for (int m = 0; m < 6; ++m)
#pragma unroll
    for (int n = 0; n < 4; ++n) acc[m][n] = zero;
  short8 aF[6][2], bA[2][2][2], bB[2][2][2];

#define LDA12(BB) do { _Pragma("unroll") for (int mp = 0; mp < 6; ++mp) { \
    _Pragma("unroll") for (int ks = 0; ks < 2; ++ks) \
      aF[mp][ks] = *(const short8*)(smem + (BB) + ks * 12288 + mp * 1024 + aBase); } } while (0)
#define LDBG(D, KOFF) do { _Pragma("unroll") for (int nh = 0; nh < 2; ++nh) { \
    _Pragma("unroll") for (int np = 0; np < 2; ++np) { \
      _Pragma("unroll") for (int ks = 0; ks < 2; ++ks) \
        D[nh][np][ks] = *(const short8*)(bGlob + (size_t)(nh * 32 + np * 16) * 4096 + (KOFF) + ks * 32); } } } while (0)
#define QUAD24(NH, FB) do { _Pragma("unroll") for (int mp = 0; mp < 6; ++mp) { \
    _Pragma("unroll") for (int np = 0; np < 2; ++np) { \
      _Pragma("unroll") for (int ks = 0; ks < 2; ++ks) \
        acc[mp][(NH)*2+np] = __builtin_amdgcn_mfma_f32_16x16x32_bf16( \
            aF[mp][ks], FB[(NH)][np][ks], acc[mp][(NH)*2+np], 0, 0, 0); } } } while (0)
#define BARR do { __builtin_amdgcn_s_barrier(); asm volatile("" ::: "memory"); } while (0)
#define WAITV(N) do { asm volatile("s_waitcnt vmcnt(" #N ")" ::: "memory"); \
    __builtin_amdgcn_sched_barrier(0); } while (0)
#define PRIO1 __builtin_amdgcn_s_setprio(1)
#define PRIO0 __builtin_amdgcn_s_setprio(0)

  // prologue: A0 -> buf0 [6]; B0 -> bA [8]; A1 -> buf1 [6]; drain A0
  STGA6(0);
  LDBG(bA, 0);
  STGA6(ABUF);
  WAITV(14);                                   // leaves B0.8 + A1.6
  BARR;
  int bk = 64;                                 // next B batch element offset

  const int nit2 = 32;                         // 64 KTs, 2 per iteration
  for (int t2 = 0; t2 < nit2; ++t2) {
    const bool morA = (t2 + 1 < nit2);
    // ---- KT even (buf0, uses bA) ----
    LDA12(0);
    LDBG(bB, bk); bk += 64;                    // B(t+1), always exists
    PRIO1; QUAD24(0, bA); PRIO0;
    BARR;                                      // seals all waves' buf0 reads
    if (morA) STGA6(0);                        // A(t+2) -> buf0
    PRIO1; QUAD24(1, bA); PRIO0;
    if (morA) { WAITV(14); } else { WAITV(8); } // drain A(t+1)+B(t)
    BARR;
    // ---- KT odd (buf1, uses bB) ----
    LDA12(ABUF);
    if (morA) { LDBG(bA, bk); bk += 64; }      // B(t+2)
    PRIO1; QUAD24(0, bB); PRIO0;
    BARR;
    if (morA) STGA6(ABUF);                     // A(t+3) -> buf1
    PRIO1; QUAD24(1, bB); PRIO0;
    if (morA) { WAITV(14); } else { WAITV(0); }
    BARR;
  }

  // ---- epilogue: out += acc + bias (single writer, no atomics) ----
  float bv[4];
#pragma unroll
  for (int n = 0; n < 4; ++n)
    bv[n] = bias[tn + wc * 64 + (n >> 1) * 32 + (n & 1) * 16 + (l & 15)];
#pragma unroll
  for (int m = 0; m < 6; ++m) {
    const int row = tm + wr * 96 + m * 16 + (l >> 4) * 4;
#pragma unroll
    for (int n = 0; n < 4; ++n) {
      const int col = tn + wc * 64 + (n >> 1) * 32 + (n & 1) * 16 + (l & 15);
      float* po = outp + (size_t)row * EMBED + col;
#pragma unroll
      for (int ri = 0; ri < 4; ++ri)
        po[(size_t)ri * EMBED] += acc[m][n][ri] + bv[n];
    }
  }
}

// ---- launch -------------------------------------------------------------

extern "C" void kernel_launch(void* const* d_in, const int* in_sizes, int n_in,
                              void* d_out, int out_size, void* d_ws, size_t ws_size,
                              hipStream_t stream) {
  const float* xg[3] = {(const float*)d_in[0], (const float*)d_in[3], (const float*)d_in[6]};
  const float* mg[3] = {(const float*)d_in[1], (const float*)d_in[4], (const float*)d_in[7]};
  const float* tg[3] = {(const float*)d_in[2], (const float*)d_in[5], (const float*)d_in[8]};
  const int* idxg[3] = {(const int*)d_in[9], (const int*)d_in[10], (const int*)d_in[11]};
  const float* W_lin = (const float*)d_in[12];
  const float* b_lin = (const float*)d_in[13];
  const float* W_res = (const float*)d_in[14];
  const float* b_res = (const float*)d_in[15];
  const float* W_out = (const float*)d_in[16];
  const float* b_out = (const float*)d_in[17];
  float* out = (float*)d_out;

  char* ws = (char*)d_ws;
  size_t off = 0;
  auto alloc = [&](size_t b) -> char* {
    size_t o = (off + 255) & ~(size_t)255;
    off = o + b;
    return ws + o;
  };

  ushort_t* hidden = (ushort_t*)alloc((size_t)MROWS * INTER * 2);   // 201 MB
  const int Kp[3] = {64, 96, 192};
  ushort_t* xsw[3];
  ushort_t* wcat[3];
  for (int g = 0; g < 3; ++g) xsw[g]  = (ushort_t*)alloc((size_t)8192 * Kp[g] * 2);
  for (int g = 0; g < 3; ++g) wcat[g] = (ushort_t*)alloc((size_t)NCAT * Kp[g] * 2);
  ushort_t* wout = (ushort_t*)alloc((size_t)EMBED * INTER * 2);     // 8 MB
  float* bcat = (float*)alloc((size_t)NCAT * 4);

  // merged preps: 2 dispatches
  const int wTotal = NCAT + EMBED * INTER + NCAT * 352;   // 6,001,664
  prep_w<<<(wTotal + 255) / 256, 256, 0, stream>>>(
      W_lin, W_res, W_out, b_lin, b_res, wout, wcat[0], wcat[1], wcat[2], bcat);
  const int xTotal = 8192 * 352;                          // 2,883,584
  prep_x<<<(xTotal + 255) / 256, 256, 0, stream>>>(
      xg[0], mg[0], tg[0], xg[1], mg[1], tg[1], xg[2], mg[2], tg[2],
      xsw[0], xsw[1], xsw[2]);

  // phase 1: all 3 groups in ONE dispatch: [8192 x Kp] @ [5120 x Kp]^T each
  gemm128p1g<<<dim3(192, 40), 256, 0, stream>>>(
      xsw[0], xsw[1], xsw[2], wcat[0], wcat[1], wcat[2], bcat,
      hidden, out, idxg[0], idxg[1], idxg[2]);
  // phase 2: [24576 x 4096] @ [1024 x 4096]^T, full K, out += acc + b_out
  gemm192x128<<<dim3(1024), 256, 0, stream>>>(hidden, wout, b_out, out);
}